// Round 6
// baseline (179.061 us; speedup 1.0000x reference)
//
#include <hip/hip_runtime.h>
#include <hip/hip_bf16.h>
#include <stdint.h>

// PatchedVisionExpertMLP — round 22
//   r21 = 177.1us best (p2 single-buffer conversion won ~6us; p1 launch_bounds
//   neutral). New theory: p1 FETCH=70MB vs ~42MB ideal; excess ~28MB = 0.8x of
//   H size -> write-allocate on the 2-byte scalar epilogue stores (each 128B
//   line filled by 4 separate store insts). Fix: LDS-transpose epilogues in
//   p1+p2 — silu'd bf16 tile staged into the (dead) 32KiB K-loop LDS with
//   padded stride, then full-line us8 stores (16B/lane). Decisive counter:
//   FETCH_SIZE must drop toward ~45MB; if unchanged, theory falsified, revert.
//   Everything else frozen at r21.

#define TOKENS 4096
#define SEQ    2048
#define DIM    1024
#define FFDIM  4096
#define MAXPAD 4608

typedef __attribute__((ext_vector_type(8))) short bf16x8;
typedef __attribute__((ext_vector_type(4))) float f32x4;

#define GAS __attribute__((address_space(1)))
#define LAS __attribute__((address_space(3)))

__device__ inline unsigned short f2bf(float x) {
    union { float f; unsigned int u; } c; c.f = x;
    unsigned int r = c.u + 0x7FFFu + ((c.u >> 16) & 1u);  // RNE
    return (unsigned short)(r >> 16);
}
__device__ inline float bf2f(unsigned short u) {
    union { unsigned int i; float f; } c; c.i = ((unsigned int)u) << 16;
    return c.f;
}

struct __align__(16) us8 { unsigned short v[8]; };

// ---------- scan: group tokens by expert, pad each segment to 128 ----------
__global__ __launch_bounds__(1024) void scan_kernel(const int* __restrict__ tt,
                                                    int* __restrict__ src_of,
                                                    int* __restrict__ counts) {
    __shared__ int wsum[16];
    const int tid  = threadIdx.x;
    const int lane = tid & 63;
    const int wav  = tid >> 6;

    for (int i = tid; i < MAXPAD; i += 1024) src_of[i] = -1;

    const int t0 = tid * 4;
    int v[4], cnt = 0;
#pragma unroll
    for (int j = 0; j < 4; ++j) {
        const int t = t0 + j;
        const int l = t & (SEQ - 1);
        int vis = 0;
        if (l < SEQ - 1) vis = (tt[t] == 1) & (tt[t + 1] == 1);
        v[j] = vis; cnt += vis;
    }

    int s = cnt;
#pragma unroll
    for (int off = 1; off < 64; off <<= 1) {
        const int o = __shfl_up(s, off, 64);
        if (lane >= off) s += o;
    }
    if (lane == 63) wsum[wav] = s;
    __syncthreads();
    if (wav == 0 && lane < 16) {
        int w = wsum[lane];
#pragma unroll
        for (int off = 1; off < 16; off <<= 1) {
            const int o = __shfl_up(w, off, 16);
            if (lane >= off) w += o;
        }
        wsum[lane] = w;
    }
    __syncthreads();

    const int wbase  = wav ? wsum[wav - 1] : 0;
    const int incl   = wbase + s;
    const int excl   = incl - cnt;
    const int totalV = wsum[15];
    const int padNv  = (totalV + 127) & ~127;
    int pv = excl;
    int pl = padNv + (t0 - excl);
#pragma unroll
    for (int j = 0; j < 4; ++j) {
        const int t = t0 + j;
        if (v[j]) src_of[pv++] = t; else src_of[pl++] = t;
    }
    if (tid == 0) {
        const int Nl = TOKENS - totalV;
        counts[0] = padNv;
        counts[1] = padNv + ((Nl + 127) & ~127);
    }
}

__device__ inline void gather_body(const float* __restrict__ hs, const int* __restrict__ src_of,
                                   unsigned short* __restrict__ Xg, int gid) {
    const int row = gid >> 7;
    const int c   = (gid & 127) * 8;
    const int src = src_of[row];
    us8 o;
    if (src >= 0) {
        const float4 a = *reinterpret_cast<const float4*>(hs + (size_t)src * DIM + c);
        const float4 b = *reinterpret_cast<const float4*>(hs + (size_t)src * DIM + c + 4);
        o.v[0] = f2bf(a.x); o.v[1] = f2bf(a.y); o.v[2] = f2bf(a.z); o.v[3] = f2bf(a.w);
        o.v[4] = f2bf(b.x); o.v[5] = f2bf(b.y); o.v[6] = f2bf(b.z); o.v[7] = f2bf(b.w);
    } else {
#pragma unroll
        for (int j = 0; j < 8; ++j) o.v[j] = 0;
    }
    *reinterpret_cast<us8*>(Xg + (size_t)row * DIM + c) = o;
}

__global__ void gather_cast(const float* __restrict__ hs, const int* __restrict__ src_of,
                            unsigned short* __restrict__ Xg) {
    gather_body(hs, src_of, Xg, blockIdx.x * 256 + threadIdx.x);
}

__device__ inline void cast8(const float* __restrict__ in, unsigned short* __restrict__ out, int i) {
    const float4 a = *reinterpret_cast<const float4*>(in + i);
    const float4 b = *reinterpret_cast<const float4*>(in + i + 4);
    us8 o;
    o.v[0] = f2bf(a.x); o.v[1] = f2bf(a.y); o.v[2] = f2bf(a.z); o.v[3] = f2bf(a.w);
    o.v[4] = f2bf(b.x); o.v[5] = f2bf(b.y); o.v[6] = f2bf(b.z); o.v[7] = f2bf(b.w);
    *reinterpret_cast<us8*>(out + i) = o;
}

// ---------- fused prep: y==0 -> gather+cast X; y=1..6 -> cast weight matrix ----------
__global__ void prep_kernel(const float* __restrict__ hs, const int* __restrict__ src_of,
                            unsigned short* __restrict__ Xg,
                            const float* __restrict__ s0, const float* __restrict__ s1,
                            const float* __restrict__ s2, const float* __restrict__ s3,
                            const float* __restrict__ s4, const float* __restrict__ s5,
                            unsigned short* __restrict__ d0, unsigned short* __restrict__ d1,
                            unsigned short* __restrict__ d2, unsigned short* __restrict__ d3,
                            unsigned short* __restrict__ d4, unsigned short* __restrict__ d5) {
    const int m = blockIdx.y;
    if (m == 0) {
        gather_body(hs, src_of, Xg, blockIdx.x * 256 + threadIdx.x);
    } else {
        const int i = (blockIdx.x * 256 + threadIdx.x) * 8;
        if (i >= FFDIM * DIM) return;
        const float* s = (m == 1) ? s0 : (m == 2) ? s1 : (m == 3) ? s2 : (m == 4) ? s3 : (m == 5) ? s4 : s5;
        unsigned short* d = (m == 1) ? d0 : (m == 2) ? d1 : (m == 3) ? d2 : (m == 4) ? d3 : (m == 5) ? d4 : d5;
        cast8(s, d, i);
    }
}

__global__ void cast4_kernel(const float* __restrict__ s0, const float* __restrict__ s1,
                             const float* __restrict__ s2, const float* __restrict__ s3,
                             unsigned short* __restrict__ d0, unsigned short* __restrict__ d1,
                             unsigned short* __restrict__ d2, unsigned short* __restrict__ d3) {
    const int i = (blockIdx.x * 256 + threadIdx.x) * 8;
    const int m = blockIdx.y;
    const float* s = (m == 0) ? s0 : (m == 1) ? s1 : (m == 2) ? s2 : s3;
    unsigned short* d = (m == 0) ? d0 : (m == 1) ? d1 : (m == 2) ? d2 : d3;
    cast8(s, d, i);
}

__global__ void cast2_kernel(const float* __restrict__ s0, const float* __restrict__ s1,
                             unsigned short* __restrict__ d0, unsigned short* __restrict__ d1) {
    const int i = (blockIdx.x * 256 + threadIdx.x) * 8;
    const float* s = blockIdx.y ? s1 : s0;
    unsigned short* d = blockIdx.y ? d1 : d0;
    cast8(s, d, i);
}

// ========== PHASE 1: 128x(64g|64u) GEMM, BK=64, 32 KiB LDS, vmcnt(0) ==========
// r16-proven K-loop; NEW: LDS-transpose epilogue -> full-line us8 H stores.
__global__ __launch_bounds__(256, 4) void gemm_p1(
    const unsigned short* __restrict__ A,
    const unsigned short* __restrict__ B0_v, const unsigned short* __restrict__ B1_v,
    const unsigned short* __restrict__ B0_l, const unsigned short* __restrict__ B1_l,
    unsigned short* __restrict__ H,
    const int* __restrict__ counts)
{
    __shared__ unsigned short Ls[256 * 64];   // 32 KiB (K-loop; reused by epilogue)

    const int m0 = blockIdx.y * 128;
    const int padNv = counts[0], padTot = counts[1];
    if (m0 >= padTot) return;
    const int expert = (m0 >= padNv);
    const unsigned short* B0 = expert ? B0_l : B0_v;
    const unsigned short* B1 = expert ? B1_l : B1_v;

    const int tid  = threadIdx.x;
    const int wid  = tid >> 6;
    const int lane = tid & 63;
    const int n0   = blockIdx.x * 64;

    constexpr int NI = 8;
    const unsigned short* src[NI];
    int loff[NI];
    const int cs = ((lane & 7) ^ (lane >> 3)) * 8;   // pre-swizzled chunk (elems)
#pragma unroll
    for (int i = 0; i < NI; ++i) {
        const int g = wid * 64 + i * 8 + (lane >> 3);  // 0..255
        const unsigned short* p;
        if (g < 128) {
            p = A + (size_t)(m0 + g) * DIM;
        } else {
            const int br = g - 128;
            p = (br < 64) ? (B0 + (size_t)(n0 + br) * DIM) : (B1 + (size_t)(n0 + br - 64) * DIM);
        }
        src[i] = p + cs;
        loff[i] = (wid * 64 + i * 8) * 64;             // shorts, wave-uniform
    }

    const int rlo = lane & 15;
    const int sw7 = rlo & 7;

    f32x4 acc[2][8];
#pragma unroll
    for (int i = 0; i < 2; ++i)
#pragma unroll
        for (int j = 0; j < 8; ++j)
            acc[i][j] = (f32x4){0.f, 0.f, 0.f, 0.f};

    const int NKT = DIM / 64;   // 16
#pragma unroll 1
    for (int kt = 0; kt < NKT; ++kt) {
        if (kt) __syncthreads();
        const int c = kt * 64;
#pragma unroll
        for (int i = 0; i < NI; ++i)
            __builtin_amdgcn_global_load_lds((const GAS void*)(src[i] + c),
                                             (LAS void*)&Ls[loff[i]], 16, 0, 0);
        asm volatile("s_waitcnt vmcnt(0)" ::: "memory");
        __syncthreads();

#pragma unroll
        for (int kh = 0; kh < 2; ++kh) {
            const int kc    = (lane >> 4) + kh * 4;
            const int swoff = (kc ^ sw7) * 8;
            const bf16x8 af0 = *reinterpret_cast<const bf16x8*>(&Ls[(wid * 32 + rlo) * 64 + swoff]);
            const bf16x8 af1 = *reinterpret_cast<const bf16x8*>(&Ls[(wid * 32 + 16 + rlo) * 64 + swoff]);
#pragma unroll
            for (int n = 0; n < 8; ++n) {
                const bf16x8 bfr = *reinterpret_cast<const bf16x8*>(&Ls[(128 + n * 16 + rlo) * 64 + swoff]);
                acc[0][n] = __builtin_amdgcn_mfma_f32_16x16x32_bf16(af0, bfr, acc[0][n], 0, 0, 0);
                acc[1][n] = __builtin_amdgcn_mfma_f32_16x16x32_bf16(af1, bfr, acc[1][n], 0, 0, 0);
            }
        }
    }

    // ---- coalesced epilogue: silu -> LDS (stride 72, 16B-aligned rows) -> us8 stores ----
    __syncthreads();   // K-loop LDS reads done everywhere; Ls reusable
    {
        constexpr int ES = 72;              // padded row stride in shorts (144B, %16==0)
        const int hi  = lane >> 4;
        const int cin = lane & 15;
#pragma unroll
        for (int fr = 0; fr < 2; ++fr)
#pragma unroll
            for (int reg = 0; reg < 4; ++reg) {
                const int rloc = wid * 32 + hi * 4 + fr * 16 + reg;   // 0..127
#pragma unroll
                for (int n = 0; n < 4; ++n) {
                    const float g = acc[fr][n][reg];
                    const float u = acc[fr][n + 4][reg];
                    const float h = g / (1.0f + __expf(-g)) * u;
                    Ls[rloc * ES + n * 16 + cin] = f2bf(h);
                }
            }
        __syncthreads();
#pragma unroll
        for (int k = 0; k < 4; ++k) {
            const int c    = tid + 256 * k;     // 0..1023
            const int row  = c >> 3;            // 0..127
            const int coff = (c & 7) * 8;       // 0..56
            const us8 o = *reinterpret_cast<const us8*>(&Ls[row * ES + coff]);
            *reinterpret_cast<us8*>(&H[(size_t)(m0 + row) * FFDIM + n0 + coff]) = o;
        }
    }
}

// ========== PHASE 2: 128x128 down-proj, split-K=2, BK=64, single 32 KiB buffer ==========
// r21 K-loop; NEW: LDS-transpose epilogue (two 64-row passes) -> us8 Part stores.
__global__ __launch_bounds__(256, 4) void gemm_p2(
    const unsigned short* __restrict__ A,
    const unsigned short* __restrict__ Bd_v, const unsigned short* __restrict__ Bd_l,
    unsigned short* __restrict__ P,
    const int* __restrict__ counts)
{
    __shared__ unsigned short Ls[256 * 64];   // 32 KiB (K-loop; reused by epilogue)

    const int m0 = blockIdx.y * 128;
    const int padNv = counts[0], padTot = counts[1];
    if (m0 >= padTot) return;
    const unsigned short* B0 = (m0 >= padNv) ? Bd_l : Bd_v;

    const int tid  = threadIdx.x;
    const int wid  = tid >> 6;
    const int lane = tid & 63;
    const int wr   = wid >> 1;
    const int wc   = wid & 1;
    const int n0   = blockIdx.x * 128;
    const int kbase = blockIdx.z * (FFDIM / 2);

    constexpr int NI = 8;
    const unsigned short* src[NI];
    int loff[NI];
    const int cs = ((lane & 7) ^ (lane >> 3)) * 8;
#pragma unroll
    for (int i = 0; i < NI; ++i) {
        const int g = wid * 64 + i * 8 + (lane >> 3);   // 0..255
        const unsigned short* p = (g < 128)
            ? A + (size_t)(m0 + g) * FFDIM
            : B0 + (size_t)(n0 + g - 128) * FFDIM;
        src[i] = p + kbase + cs;
        loff[i] = (wid * 64 + i * 8) * 64;
    }

    const int rlo = lane & 15;
    const int sw7 = rlo & 7;

    f32x4 acc[4][4];
#pragma unroll
    for (int i = 0; i < 4; ++i)
#pragma unroll
        for (int j = 0; j < 4; ++j)
            acc[i][j] = (f32x4){0.f, 0.f, 0.f, 0.f};

    const int NKT = (FFDIM / 2) / 64;  // 32
    bf16x8 af[4], bf[4];
#pragma unroll 1
    for (int kt = 0; kt < NKT; ++kt) {
        if (kt) __syncthreads();
        const int c = kt * 64;
#pragma unroll
        for (int i = 0; i < NI; ++i)
            __builtin_amdgcn_global_load_lds((const GAS void*)(src[i] + c),
                                             (LAS void*)&Ls[loff[i]], 16, 0, 0);
        asm volatile("s_waitcnt vmcnt(0)" ::: "memory");
        __syncthreads();

#pragma unroll
        for (int kh = 0; kh < 2; ++kh) {
            const int kc    = (lane >> 4) + kh * 4;
            const int swoff = (kc ^ sw7) * 8;
#pragma unroll
            for (int i = 0; i < 4; ++i)
                af[i] = *reinterpret_cast<const bf16x8*>(&Ls[(wr * 64 + i * 16 + rlo) * 64 + swoff]);
#pragma unroll
            for (int j = 0; j < 4; ++j)
                bf[j] = *reinterpret_cast<const bf16x8*>(&Ls[(128 + wc * 64 + j * 16 + rlo) * 64 + swoff]);

#pragma unroll
            for (int i = 0; i < 4; ++i)
#pragma unroll
                for (int j = 0; j < 4; ++j)
                    acc[i][j] = __builtin_amdgcn_mfma_f32_16x16x32_bf16(af[i], bf[j], acc[i][j], 0, 0, 0);
        }
    }

    // ---- coalesced epilogue: two 64-row passes through LDS (stride 136) ----
    unsigned short* Pz = P + (size_t)blockIdx.z * MAXPAD * DIM;
    {
        constexpr int ES = 136;             // 128+8 shorts (272B, %16==0)
        const int hi  = lane >> 4;
        const int cin = lane & 15;
#pragma unroll 1
        for (int p = 0; p < 2; ++p) {
            __syncthreads();                // LDS free (K-loop or prior pass done)
            if (wr == p) {
#pragma unroll
                for (int i = 0; i < 4; ++i)
#pragma unroll
                    for (int reg = 0; reg < 4; ++reg) {
                        const int rloc = hi * 4 + i * 16 + reg;       // 0..63
#pragma unroll
                        for (int j = 0; j < 4; ++j)
                            Ls[rloc * ES + wc * 64 + j * 16 + cin] = f2bf(acc[i][j][reg]);
                    }
            }
            __syncthreads();
#pragma unroll
            for (int k = 0; k < 4; ++k) {
                const int c    = tid + 256 * k;    // 0..1023
                const int row  = c >> 4;           // 0..63
                const int coff = (c & 15) * 8;     // 0..120
                const us8 o = *reinterpret_cast<const us8*>(&Ls[row * ES + coff]);
                *reinterpret_cast<us8*>(&Pz[(size_t)(m0 + p * 64 + row) * DIM + n0 + coff]) = o;
            }
        }
    }
}

// ---------- reduce: out[src_of[row]] = f32(P0[row]) + f32(P1[row]) ----------
__global__ void reduce_kernel(const unsigned short* __restrict__ P,
                              const int* __restrict__ src_of,
                              float* __restrict__ O) {
    const int gid = blockIdx.x * 256 + threadIdx.x;   // MAXPAD*128 threads
    const int row = gid >> 7;
    const int c   = (gid & 127) * 8;
    const int src = src_of[row];
    if (src < 0) return;
    const us8 a = *reinterpret_cast<const us8*>(P + (size_t)row * DIM + c);
    const us8 b = *reinterpret_cast<const us8*>(P + (size_t)(MAXPAD + row) * DIM + c);
    float4 o0, o1;
    o0.x = bf2f(a.v[0]) + bf2f(b.v[0]);
    o0.y = bf2f(a.v[1]) + bf2f(b.v[1]);
    o0.z = bf2f(a.v[2]) + bf2f(b.v[2]);
    o0.w = bf2f(a.v[3]) + bf2f(b.v[3]);
    o1.x = bf2f(a.v[4]) + bf2f(b.v[4]);
    o1.y = bf2f(a.v[5]) + bf2f(b.v[5]);
    o1.z = bf2f(a.v[6]) + bf2f(b.v[6]);
    o1.w = bf2f(a.v[7]) + bf2f(b.v[7]);
    float* dst = O + (size_t)src * DIM + c;
    *reinterpret_cast<float4*>(dst)     = o0;
    *reinterpret_cast<float4*>(dst + 4) = o1;
}

extern "C" void kernel_launch(void* const* d_in, const int* in_sizes, int n_in,
                              void* d_out, int out_size, void* d_ws, size_t ws_size,
                              hipStream_t stream) {
    const float* hs = (const float*)d_in[0];
    const int*   tt = (const int*)d_in[1];
    const float* w_vg = (const float*)d_in[2];
    const float* w_vu = (const float*)d_in[3];
    const float* w_vd = (const float*)d_in[4];
    const float* w_lg = (const float*)d_in[5];
    const float* w_lu = (const float*)d_in[6];
    const float* w_ld = (const float*)d_in[7];
    float* out = (float*)d_out;
    char* ws = (char*)d_ws;

    const size_t MATB = (size_t)FFDIM * DIM * 2;             // 8 MiB
    const size_t XGB  = (size_t)MAXPAD * DIM * 2;            // 9.44 MB
    const size_t HSZ  = (size_t)MAXPAD * FFDIM * 2;          // 37.75 MB

    int* counts = (int*)ws;
    int* src_of = (int*)(ws + 64);
    unsigned short* Xg = (unsigned short*)(ws + 32768);

    const int NELEM = FFDIM * DIM;
    const size_t need_big = 32768 + XGB + 6 * MATB + HSZ;    // ~93 MiB

    scan_kernel<<<1, 1024, 0, stream>>>(tt, src_of, counts);

    if (ws_size >= need_big) {
        // big layout: all 6 weights own slots; Part aliases dead gate/up region
        unsigned short* Wg_v = (unsigned short*)(ws + 32768 + XGB);
        unsigned short* Wu_v = (unsigned short*)(ws + 32768 + XGB + MATB);
        unsigned short* Wg_l = (unsigned short*)(ws + 32768 + XGB + MATB * 2);
        unsigned short* Wu_l = (unsigned short*)(ws + 32768 + XGB + MATB * 3);
        unsigned short* Wd_v = (unsigned short*)(ws + 32768 + XGB + MATB * 4);
        unsigned short* Wd_l = (unsigned short*)(ws + 32768 + XGB + MATB * 5);
        unsigned short* H    = (unsigned short*)(ws + 32768 + XGB + MATB * 6);
        unsigned short* Part = Wg_v;   // 18.9 MB over 32 MB dead-after-p1 region

        dim3 gp(MAXPAD * 128 / 256, 7);
        prep_kernel<<<gp, 256, 0, stream>>>(hs, src_of, Xg,
                                            w_vg, w_vu, w_lg, w_lu, w_vd, w_ld,
                                            Wg_v, Wu_v, Wg_l, Wu_l, Wd_v, Wd_l);

        dim3 g1(FFDIM / 64, MAXPAD / 128);    // 64 x 36
        gemm_p1<<<g1, 256, 0, stream>>>(Xg, Wg_v, Wu_v, Wg_l, Wu_l, H, counts);

        dim3 g2(DIM / 128, MAXPAD / 128, 2);  // 8 x 36 x 2
        gemm_p2<<<g2, 256, 0, stream>>>(H, Wd_v, Wd_l, Part, counts);

        reduce_kernel<<<MAXPAD * 128 / 256, 256, 0, stream>>>(Part, src_of, out);
    } else {
        // fallback: r15/r16 layout/order (Wd + Part alias dead regions)
        unsigned short* Wg_v = (unsigned short*)(ws + 32768 + XGB);
        unsigned short* Wu_v = (unsigned short*)(ws + 32768 + XGB + MATB);
        unsigned short* Wg_l = (unsigned short*)(ws + 32768 + XGB + MATB * 2);
        unsigned short* Wu_l = (unsigned short*)(ws + 32768 + XGB + MATB * 3);
        unsigned short* H    = (unsigned short*)(ws + 32768 + XGB + MATB * 4);
        unsigned short* Wd_v = (unsigned short*)(ws + 32768);
        unsigned short* Wd_l = (unsigned short*)(ws + 32768 + MATB);
        unsigned short* Part = (unsigned short*)(ws + 32768 + MATB * 2);

        gather_cast<<<MAXPAD * 128 / 256, 256, 0, stream>>>(hs, src_of, Xg);

        dim3 gc4(NELEM / 2048, 4);
        cast4_kernel<<<gc4, 256, 0, stream>>>(w_vg, w_vu, w_lg, w_lu, Wg_v, Wu_v, Wg_l, Wu_l);

        dim3 g1(FFDIM / 64, MAXPAD / 128);
        gemm_p1<<<g1, 256, 0, stream>>>(Xg, Wg_v, Wu_v, Wg_l, Wu_l, H, counts);

        dim3 gc2(NELEM / 2048, 2);
        cast2_kernel<<<gc2, 256, 0, stream>>>(w_vd, w_ld, Wd_v, Wd_l);

        dim3 g2(DIM / 128, MAXPAD / 128, 2);
        gemm_p2<<<g2, 256, 0, stream>>>(H, Wd_v, Wd_l, Part, counts);

        reduce_kernel<<<MAXPAD * 128 / 256, 256, 0, stream>>>(Part, src_of, out);
    }
}

// Round 7
// 177.203 us; speedup vs baseline: 1.0105x; 1.0105x over previous
//
#include <hip/hip_runtime.h>
#include <hip/hip_bf16.h>
#include <stdint.h>

// PatchedVisionExpertMLP — round 23
//   r22 falsified the write-allocate theory (FETCH unchanged, +bank conflicts);
//   LDS epilogues reverted to r21 scalar stores. This round: FUSE reduce into
//   p2. p2 becomes 128x64 tile, full K=4096 (p1's exact proven K-loop, NI=6,
//   24 KiB LDS), epilogue scatters f32 directly to out[src_of[row]]. Removes
//   Part double-write (37.8MB) + reduce re-read (37.8MB) + one kernel launch.
//   Grid 16x36=576 blocks (same residency as old split-K p2). p1 = r21 exact.

#define TOKENS 4096
#define SEQ    2048
#define DIM    1024
#define FFDIM  4096
#define MAXPAD 4608

typedef __attribute__((ext_vector_type(8))) short bf16x8;
typedef __attribute__((ext_vector_type(4))) float f32x4;

#define GAS __attribute__((address_space(1)))
#define LAS __attribute__((address_space(3)))

__device__ inline unsigned short f2bf(float x) {
    union { float f; unsigned int u; } c; c.f = x;
    unsigned int r = c.u + 0x7FFFu + ((c.u >> 16) & 1u);  // RNE
    return (unsigned short)(r >> 16);
}
__device__ inline float bf2f(unsigned short u) {
    union { unsigned int i; float f; } c; c.i = ((unsigned int)u) << 16;
    return c.f;
}

struct __align__(16) us8 { unsigned short v[8]; };

// ---------- scan: group tokens by expert, pad each segment to 128 ----------
__global__ __launch_bounds__(1024) void scan_kernel(const int* __restrict__ tt,
                                                    int* __restrict__ src_of,
                                                    int* __restrict__ counts) {
    __shared__ int wsum[16];
    const int tid  = threadIdx.x;
    const int lane = tid & 63;
    const int wav  = tid >> 6;

    for (int i = tid; i < MAXPAD; i += 1024) src_of[i] = -1;

    const int t0 = tid * 4;
    int v[4], cnt = 0;
#pragma unroll
    for (int j = 0; j < 4; ++j) {
        const int t = t0 + j;
        const int l = t & (SEQ - 1);
        int vis = 0;
        if (l < SEQ - 1) vis = (tt[t] == 1) & (tt[t + 1] == 1);
        v[j] = vis; cnt += vis;
    }

    int s = cnt;
#pragma unroll
    for (int off = 1; off < 64; off <<= 1) {
        const int o = __shfl_up(s, off, 64);
        if (lane >= off) s += o;
    }
    if (lane == 63) wsum[wav] = s;
    __syncthreads();
    if (wav == 0 && lane < 16) {
        int w = wsum[lane];
#pragma unroll
        for (int off = 1; off < 16; off <<= 1) {
            const int o = __shfl_up(w, off, 16);
            if (lane >= off) w += o;
        }
        wsum[lane] = w;
    }
    __syncthreads();

    const int wbase  = wav ? wsum[wav - 1] : 0;
    const int incl   = wbase + s;
    const int excl   = incl - cnt;
    const int totalV = wsum[15];
    const int padNv  = (totalV + 127) & ~127;
    int pv = excl;
    int pl = padNv + (t0 - excl);
#pragma unroll
    for (int j = 0; j < 4; ++j) {
        const int t = t0 + j;
        if (v[j]) src_of[pv++] = t; else src_of[pl++] = t;
    }
    if (tid == 0) {
        const int Nl = TOKENS - totalV;
        counts[0] = padNv;
        counts[1] = padNv + ((Nl + 127) & ~127);
    }
}

__device__ inline void gather_body(const float* __restrict__ hs, const int* __restrict__ src_of,
                                   unsigned short* __restrict__ Xg, int gid) {
    const int row = gid >> 7;
    const int c   = (gid & 127) * 8;
    const int src = src_of[row];
    us8 o;
    if (src >= 0) {
        const float4 a = *reinterpret_cast<const float4*>(hs + (size_t)src * DIM + c);
        const float4 b = *reinterpret_cast<const float4*>(hs + (size_t)src * DIM + c + 4);
        o.v[0] = f2bf(a.x); o.v[1] = f2bf(a.y); o.v[2] = f2bf(a.z); o.v[3] = f2bf(a.w);
        o.v[4] = f2bf(b.x); o.v[5] = f2bf(b.y); o.v[6] = f2bf(b.z); o.v[7] = f2bf(b.w);
    } else {
#pragma unroll
        for (int j = 0; j < 8; ++j) o.v[j] = 0;
    }
    *reinterpret_cast<us8*>(Xg + (size_t)row * DIM + c) = o;
}

__global__ void gather_cast(const float* __restrict__ hs, const int* __restrict__ src_of,
                            unsigned short* __restrict__ Xg) {
    gather_body(hs, src_of, Xg, blockIdx.x * 256 + threadIdx.x);
}

__device__ inline void cast8(const float* __restrict__ in, unsigned short* __restrict__ out, int i) {
    const float4 a = *reinterpret_cast<const float4*>(in + i);
    const float4 b = *reinterpret_cast<const float4*>(in + i + 4);
    us8 o;
    o.v[0] = f2bf(a.x); o.v[1] = f2bf(a.y); o.v[2] = f2bf(a.z); o.v[3] = f2bf(a.w);
    o.v[4] = f2bf(b.x); o.v[5] = f2bf(b.y); o.v[6] = f2bf(b.z); o.v[7] = f2bf(b.w);
    *reinterpret_cast<us8*>(out + i) = o;
}

// ---------- fused prep: y==0 -> gather+cast X; y=1..6 -> cast weight matrix ----------
__global__ void prep_kernel(const float* __restrict__ hs, const int* __restrict__ src_of,
                            unsigned short* __restrict__ Xg,
                            const float* __restrict__ s0, const float* __restrict__ s1,
                            const float* __restrict__ s2, const float* __restrict__ s3,
                            const float* __restrict__ s4, const float* __restrict__ s5,
                            unsigned short* __restrict__ d0, unsigned short* __restrict__ d1,
                            unsigned short* __restrict__ d2, unsigned short* __restrict__ d3,
                            unsigned short* __restrict__ d4, unsigned short* __restrict__ d5) {
    const int m = blockIdx.y;
    if (m == 0) {
        gather_body(hs, src_of, Xg, blockIdx.x * 256 + threadIdx.x);
    } else {
        const int i = (blockIdx.x * 256 + threadIdx.x) * 8;
        if (i >= FFDIM * DIM) return;
        const float* s = (m == 1) ? s0 : (m == 2) ? s1 : (m == 3) ? s2 : (m == 4) ? s3 : (m == 5) ? s4 : s5;
        unsigned short* d = (m == 1) ? d0 : (m == 2) ? d1 : (m == 3) ? d2 : (m == 4) ? d3 : (m == 5) ? d4 : d5;
        cast8(s, d, i);
    }
}

__global__ void cast4_kernel(const float* __restrict__ s0, const float* __restrict__ s1,
                             const float* __restrict__ s2, const float* __restrict__ s3,
                             unsigned short* __restrict__ d0, unsigned short* __restrict__ d1,
                             unsigned short* __restrict__ d2, unsigned short* __restrict__ d3) {
    const int i = (blockIdx.x * 256 + threadIdx.x) * 8;
    const int m = blockIdx.y;
    const float* s = (m == 0) ? s0 : (m == 1) ? s1 : (m == 2) ? s2 : s3;
    unsigned short* d = (m == 0) ? d0 : (m == 1) ? d1 : (m == 2) ? d2 : d3;
    cast8(s, d, i);
}

__global__ void cast2_kernel(const float* __restrict__ s0, const float* __restrict__ s1,
                             unsigned short* __restrict__ d0, unsigned short* __restrict__ d1) {
    const int i = (blockIdx.x * 256 + threadIdx.x) * 8;
    const float* s = blockIdx.y ? s1 : s0;
    unsigned short* d = blockIdx.y ? d1 : d0;
    cast8(s, d, i);
}

// ========== PHASE 1: 128x(64g|64u) GEMM, BK=64, 32 KiB LDS, vmcnt(0) (r21) ==========
__global__ __launch_bounds__(256, 4) void gemm_p1(
    const unsigned short* __restrict__ A,
    const unsigned short* __restrict__ B0_v, const unsigned short* __restrict__ B1_v,
    const unsigned short* __restrict__ B0_l, const unsigned short* __restrict__ B1_l,
    unsigned short* __restrict__ H,
    const int* __restrict__ counts)
{
    __shared__ unsigned short Ls[256 * 64];   // 32 KiB

    const int m0 = blockIdx.y * 128;
    const int padNv = counts[0], padTot = counts[1];
    if (m0 >= padTot) return;
    const int expert = (m0 >= padNv);
    const unsigned short* B0 = expert ? B0_l : B0_v;
    const unsigned short* B1 = expert ? B1_l : B1_v;

    const int tid  = threadIdx.x;
    const int wid  = tid >> 6;
    const int lane = tid & 63;
    const int n0   = blockIdx.x * 64;

    constexpr int NI = 8;
    const unsigned short* src[NI];
    int loff[NI];
    const int cs = ((lane & 7) ^ (lane >> 3)) * 8;   // pre-swizzled chunk (elems)
#pragma unroll
    for (int i = 0; i < NI; ++i) {
        const int g = wid * 64 + i * 8 + (lane >> 3);  // 0..255
        const unsigned short* p;
        if (g < 128) {
            p = A + (size_t)(m0 + g) * DIM;
        } else {
            const int br = g - 128;
            p = (br < 64) ? (B0 + (size_t)(n0 + br) * DIM) : (B1 + (size_t)(n0 + br - 64) * DIM);
        }
        src[i] = p + cs;
        loff[i] = (wid * 64 + i * 8) * 64;             // shorts, wave-uniform
    }

    const int rlo = lane & 15;
    const int sw7 = rlo & 7;

    f32x4 acc[2][8];
#pragma unroll
    for (int i = 0; i < 2; ++i)
#pragma unroll
        for (int j = 0; j < 8; ++j)
            acc[i][j] = (f32x4){0.f, 0.f, 0.f, 0.f};

    const int NKT = DIM / 64;   // 16
#pragma unroll 1
    for (int kt = 0; kt < NKT; ++kt) {
        if (kt) __syncthreads();
        const int c = kt * 64;
#pragma unroll
        for (int i = 0; i < NI; ++i)
            __builtin_amdgcn_global_load_lds((const GAS void*)(src[i] + c),
                                             (LAS void*)&Ls[loff[i]], 16, 0, 0);
        asm volatile("s_waitcnt vmcnt(0)" ::: "memory");
        __syncthreads();

#pragma unroll
        for (int kh = 0; kh < 2; ++kh) {
            const int kc    = (lane >> 4) + kh * 4;
            const int swoff = (kc ^ sw7) * 8;
            const bf16x8 af0 = *reinterpret_cast<const bf16x8*>(&Ls[(wid * 32 + rlo) * 64 + swoff]);
            const bf16x8 af1 = *reinterpret_cast<const bf16x8*>(&Ls[(wid * 32 + 16 + rlo) * 64 + swoff]);
#pragma unroll
            for (int n = 0; n < 8; ++n) {
                const bf16x8 bfr = *reinterpret_cast<const bf16x8*>(&Ls[(128 + n * 16 + rlo) * 64 + swoff]);
                acc[0][n] = __builtin_amdgcn_mfma_f32_16x16x32_bf16(af0, bfr, acc[0][n], 0, 0, 0);
                acc[1][n] = __builtin_amdgcn_mfma_f32_16x16x32_bf16(af1, bfr, acc[1][n], 0, 0, 0);
            }
        }
    }

    const int rbase = m0 + wid * 32 + ((lane >> 4) * 4);
    const int cin   = lane & 15;
#pragma unroll
    for (int fr = 0; fr < 2; ++fr)
#pragma unroll
        for (int reg = 0; reg < 4; ++reg) {
            const int row = rbase + fr * 16 + reg;
#pragma unroll
            for (int n = 0; n < 4; ++n) {
                const float g = acc[fr][n][reg];
                const float u = acc[fr][n + 4][reg];
                const float h = g / (1.0f + __expf(-g)) * u;
                H[(size_t)row * FFDIM + n0 + n * 16 + cin] = f2bf(h);
            }
        }
}

// ========== PHASE 2 (fused +reduce): 128x64 down-proj, full K=4096 ==========
// p1's exact proven K-loop (NI=6 staging, 24 KiB LDS, single buffer, vmcnt(0));
// epilogue scatters f32 directly to out[src_of[row]] — no Part, no reduce.
__global__ __launch_bounds__(256, 4) void gemm_p2(
    const unsigned short* __restrict__ A,
    const unsigned short* __restrict__ Bd_v, const unsigned short* __restrict__ Bd_l,
    const int* __restrict__ src_of,
    float* __restrict__ O,
    const int* __restrict__ counts)
{
    __shared__ unsigned short Ls[192 * 64];   // 24 KiB

    const int m0 = blockIdx.y * 128;
    const int padNv = counts[0], padTot = counts[1];
    if (m0 >= padTot) return;
    const unsigned short* B0 = (m0 >= padNv) ? Bd_l : Bd_v;

    const int tid  = threadIdx.x;
    const int wid  = tid >> 6;
    const int lane = tid & 63;
    const int n0   = blockIdx.x * 64;

    constexpr int NI = 6;
    const unsigned short* src[NI];
    int loff[NI];
    const int cs = ((lane & 7) ^ (lane >> 3)) * 8;
#pragma unroll
    for (int i = 0; i < NI; ++i) {
        const int g = wid * 48 + i * 8 + (lane >> 3);   // 0..191
        const unsigned short* p = (g < 128)
            ? A + (size_t)(m0 + g) * FFDIM
            : B0 + (size_t)(n0 + g - 128) * FFDIM;
        src[i] = p + cs;
        loff[i] = (wid * 48 + i * 8) * 64;
    }

    const int rlo = lane & 15;
    const int sw7 = rlo & 7;

    f32x4 acc[2][4];
#pragma unroll
    for (int i = 0; i < 2; ++i)
#pragma unroll
        for (int j = 0; j < 4; ++j)
            acc[i][j] = (f32x4){0.f, 0.f, 0.f, 0.f};

    const int NKT = FFDIM / 64;   // 64
#pragma unroll 1
    for (int kt = 0; kt < NKT; ++kt) {
        if (kt) __syncthreads();
        const int c = kt * 64;
#pragma unroll
        for (int i = 0; i < NI; ++i)
            __builtin_amdgcn_global_load_lds((const GAS void*)(src[i] + c),
                                             (LAS void*)&Ls[loff[i]], 16, 0, 0);
        asm volatile("s_waitcnt vmcnt(0)" ::: "memory");
        __syncthreads();

#pragma unroll
        for (int kh = 0; kh < 2; ++kh) {
            const int kc    = (lane >> 4) + kh * 4;
            const int swoff = (kc ^ sw7) * 8;
            const bf16x8 af0 = *reinterpret_cast<const bf16x8*>(&Ls[(wid * 32 + rlo) * 64 + swoff]);
            const bf16x8 af1 = *reinterpret_cast<const bf16x8*>(&Ls[(wid * 32 + 16 + rlo) * 64 + swoff]);
#pragma unroll
            for (int n = 0; n < 4; ++n) {
                const bf16x8 bfr = *reinterpret_cast<const bf16x8*>(&Ls[(128 + n * 16 + rlo) * 64 + swoff]);
                acc[0][n] = __builtin_amdgcn_mfma_f32_16x16x32_bf16(af0, bfr, acc[0][n], 0, 0, 0);
                acc[1][n] = __builtin_amdgcn_mfma_f32_16x16x32_bf16(af1, bfr, acc[1][n], 0, 0, 0);
            }
        }
    }

    // fused epilogue: scatter f32 rows directly to out via src_of (pad rows skipped)
    const int rbase = m0 + wid * 32 + ((lane >> 4) * 4);
    const int cin   = lane & 15;
#pragma unroll
    for (int fr = 0; fr < 2; ++fr)
#pragma unroll
        for (int reg = 0; reg < 4; ++reg) {
            const int row = rbase + fr * 16 + reg;
            const int s   = src_of[row];
            if (s >= 0) {
                float* dst = O + (size_t)s * DIM + n0;
#pragma unroll
                for (int n = 0; n < 4; ++n)
                    dst[n * 16 + cin] = acc[fr][n][reg];
            }
        }
}

extern "C" void kernel_launch(void* const* d_in, const int* in_sizes, int n_in,
                              void* d_out, int out_size, void* d_ws, size_t ws_size,
                              hipStream_t stream) {
    const float* hs = (const float*)d_in[0];
    const int*   tt = (const int*)d_in[1];
    const float* w_vg = (const float*)d_in[2];
    const float* w_vu = (const float*)d_in[3];
    const float* w_vd = (const float*)d_in[4];
    const float* w_lg = (const float*)d_in[5];
    const float* w_lu = (const float*)d_in[6];
    const float* w_ld = (const float*)d_in[7];
    float* out = (float*)d_out;
    char* ws = (char*)d_ws;

    const size_t MATB = (size_t)FFDIM * DIM * 2;             // 8 MiB
    const size_t XGB  = (size_t)MAXPAD * DIM * 2;            // 9.44 MB
    const size_t HSZ  = (size_t)MAXPAD * FFDIM * 2;          // 37.75 MB

    int* counts = (int*)ws;
    int* src_of = (int*)(ws + 64);
    unsigned short* Xg = (unsigned short*)(ws + 32768);

    const int NELEM = FFDIM * DIM;
    const size_t need_big = 32768 + XGB + 6 * MATB + HSZ;    // ~93 MiB

    scan_kernel<<<1, 1024, 0, stream>>>(tt, src_of, counts);

    if (ws_size >= need_big) {
        // big layout: all 6 weights own slots
        unsigned short* Wg_v = (unsigned short*)(ws + 32768 + XGB);
        unsigned short* Wu_v = (unsigned short*)(ws + 32768 + XGB + MATB);
        unsigned short* Wg_l = (unsigned short*)(ws + 32768 + XGB + MATB * 2);
        unsigned short* Wu_l = (unsigned short*)(ws + 32768 + XGB + MATB * 3);
        unsigned short* Wd_v = (unsigned short*)(ws + 32768 + XGB + MATB * 4);
        unsigned short* Wd_l = (unsigned short*)(ws + 32768 + XGB + MATB * 5);
        unsigned short* H    = (unsigned short*)(ws + 32768 + XGB + MATB * 6);

        dim3 gp(MAXPAD * 128 / 256, 7);
        prep_kernel<<<gp, 256, 0, stream>>>(hs, src_of, Xg,
                                            w_vg, w_vu, w_lg, w_lu, w_vd, w_ld,
                                            Wg_v, Wu_v, Wg_l, Wu_l, Wd_v, Wd_l);

        dim3 g1(FFDIM / 64, MAXPAD / 128);    // 64 x 36
        gemm_p1<<<g1, 256, 0, stream>>>(Xg, Wg_v, Wu_v, Wg_l, Wu_l, H, counts);

        dim3 g2(DIM / 64, MAXPAD / 128);      // 16 x 36, fused reduce
        gemm_p2<<<g2, 256, 0, stream>>>(H, Wd_v, Wd_l, src_of, out, counts);
    } else {
        // fallback: Wd cast after p1 into dead Xg region (r15-style aliasing)
        unsigned short* Wg_v = (unsigned short*)(ws + 32768 + XGB);
        unsigned short* Wu_v = (unsigned short*)(ws + 32768 + XGB + MATB);
        unsigned short* Wg_l = (unsigned short*)(ws + 32768 + XGB + MATB * 2);
        unsigned short* Wu_l = (unsigned short*)(ws + 32768 + XGB + MATB * 3);
        unsigned short* H    = (unsigned short*)(ws + 32768 + XGB + MATB * 4);
        unsigned short* Wd_v = (unsigned short*)(ws + 32768);
        unsigned short* Wd_l = (unsigned short*)(ws + 32768 + MATB);

        gather_cast<<<MAXPAD * 128 / 256, 256, 0, stream>>>(hs, src_of, Xg);

        dim3 gc4(NELEM / 2048, 4);
        cast4_kernel<<<gc4, 256, 0, stream>>>(w_vg, w_vu, w_lg, w_lu, Wg_v, Wu_v, Wg_l, Wu_l);

        dim3 g1(FFDIM / 64, MAXPAD / 128);
        gemm_p1<<<g1, 256, 0, stream>>>(Xg, Wg_v, Wu_v, Wg_l, Wu_l, H, counts);

        dim3 gc2(NELEM / 2048, 2);
        cast2_kernel<<<gc2, 256, 0, stream>>>(w_vd, w_ld, Wd_v, Wd_l);

        dim3 g2(DIM / 64, MAXPAD / 128);
        gemm_p2<<<g2, 256, 0, stream>>>(H, Wd_v, Wd_l, src_of, out, counts);
    }
}